// Round 5
// baseline (45.256 us; speedup 1.0000x reference)
//
#include <hip/hip_runtime.h>
#include <math.h>

// Problem constants: B=256, N=64, M=64, d=32, TOPK=10
constexpr int Bn = 256;
constexpr int Nn = 64;
constexpr int Mn = 64;
constexpr int Dn = 32;
constexpr int TK = 10;

// Correctly-rounded fp32 exp via fp64 (best proxy for numpy's expf)
__device__ __forceinline__ float exp_np(float x) {
    return (float)exp((double)x);
}

__global__ __launch_bounds__(256) void sparse_lambda_attn_kernel(
    const float* __restrict__ fv,   // [B,N,D]
    const float* __restrict__ cv,   // [B,M,D]
    const float* __restrict__ Wq,   // [D,D]
    const float* __restrict__ Wk,   // [D,D]
    const float* __restrict__ Wv,   // [D,M]
    float* __restrict__ out)        // [B, N*TK, D]
{
    // Replicate numpy fp32 semantics: NO fma contraction anywhere in this kernel.
    #pragma clang fp contract(off)

    __shared__ float f_lds[Nn][Dn];       // 8 KB
    __shared__ float c_lds[Mn][Dn];       // 8 KB
    __shared__ float bufA[Mn][Dn];        // 8 KB: K logits -> K probs -> Q
    __shared__ float buf16[Mn][Mn + 1];   // 16.25 KB: V -> weight (padded for top-k column reads)
    __shared__ float lam[Dn][Mn];         // 8 KB
    __shared__ float topw[Nn][TK];        // 2.5 KB
    __shared__ int   topi[Nn][TK];        // 2.5 KB

    const int b = blockIdx.x;
    const int tid = threadIdx.x;

    // ---- stage feature/context tiles (coalesced float4) ----
    {
        const float4* f4 = reinterpret_cast<const float4*>(fv + (size_t)b * Nn * Dn);
        const float4* c4 = reinterpret_cast<const float4*>(cv + (size_t)b * Mn * Dn);
        float4* fl = reinterpret_cast<float4*>(&f_lds[0][0]);
        float4* cl = reinterpret_cast<float4*>(&c_lds[0][0]);
        for (int i = tid; i < Nn * Dn / 4; i += 256) { fl[i] = f4[i]; cl[i] = c4[i]; }
    }
    __syncthreads();

    // ---- K logits[m][k] = sum_d c[m,d]*Wk[d,k]  (sequential mul+add, no fma) ----
    for (int i = tid; i < Mn * Dn; i += 256) {
        const int m = i >> 5, k = i & 31;
        float acc = 0.f;
        for (int d = 0; d < Dn; ++d) {
            const float p = c_lds[m][d] * Wk[d * Dn + k];
            acc = acc + p;
        }
        bufA[m][k] = acc;
    }
    // ---- V[m][v] = sum_d c[m,d]*Wv[d,v] ----
    for (int i = tid; i < Mn * Mn; i += 256) {
        const int m = i >> 6, v = i & 63;
        float acc = 0.f;
        for (int d = 0; d < Dn; ++d) {
            const float p = c_lds[m][d] * Wv[d * Mn + v];
            acc = acc + p;
        }
        buf16[m][v] = acc;
    }
    __syncthreads();

    // ---- softmax over m per column k (np semantics: max, exp, seq sum, true division) ----
    if (tid < Dn) {
        const int k = tid;
        float mx = bufA[0][k];
        for (int m = 1; m < Mn; ++m) mx = fmaxf(mx, bufA[m][k]);
        // exp array (overwrite), then ascending-m sum, then divide
        for (int m = 0; m < Mn; ++m) bufA[m][k] = exp_np(bufA[m][k] - mx);
        float s = 0.f;
        for (int m = 0; m < Mn; ++m) s = s + bufA[m][k];
        for (int m = 0; m < Mn; ++m) bufA[m][k] = bufA[m][k] / s;
    }
    __syncthreads();

    // ---- lam[k][v] = sum_m K[m][k]*V[m][v]  (sequential, no fma) ----
    for (int i = tid; i < Dn * Mn; i += 256) {
        const int k = i >> 6, v = i & 63;
        float acc = 0.f;
        for (int m = 0; m < Mn; ++m) {
            const float p = bufA[m][k] * buf16[m][v];
            acc = acc + p;
        }
        lam[k][v] = acc;
    }
    __syncthreads();   // lam done; bufA (K) and buf16 (V) now dead

    // ---- Q[n][k] = sum_d f[n,d]*Wq[d,k]  (reuse bufA) ----
    for (int i = tid; i < Nn * Dn; i += 256) {
        const int n = i >> 5, k = i & 31;
        float acc = 0.f;
        for (int d = 0; d < Dn; ++d) {
            const float p = f_lds[n][d] * Wq[d * Dn + k];
            acc = acc + p;
        }
        bufA[n][k] = acc;
    }
    __syncthreads();

    // ---- weight[n][v] = sum_k Q[n][k]*lam[k][v]  (reuse buf16) ----
    for (int i = tid; i < Nn * Mn; i += 256) {
        const int n = i >> 6, v = i & 63;
        float acc = 0.f;
        for (int k = 0; k < Dn; ++k) {
            const float p = bufA[n][k] * lam[k][v];
            acc = acc + p;
        }
        buf16[n][v] = acc;
    }
    __syncthreads();

    // ---- top-10 per row (fp32 selection; strict >, lower index wins ties = lax.top_k) ----
    if (tid < Nn) {
        const int n = tid;
        unsigned long long used = 0ull;
        float vals[TK];
        int idxs[TK];
        for (int t = 0; t < TK; ++t) {
            float best = -INFINITY;
            int bi = 0;
            for (int m = 0; m < Mn; ++m) {
                const bool avail = !((used >> m) & 1ull);
                const float v = buf16[n][m];
                if (avail && v > best) { best = v; bi = m; }
            }
            used |= (1ull << bi);
            vals[t] = best;
            idxs[t] = bi;
        }
        const float mx = vals[0];
        float ev[TK];
        float s = 0.f;
        for (int t = 0; t < TK; ++t) { ev[t] = exp_np(vals[t] - mx); s = s + ev[t]; }
        for (int t = 0; t < TK; ++t) { topw[n][t] = ev[t] / s; topi[n][t] = idxs[t]; }
    }
    __syncthreads();

    // ---- output: out[b][n*TK+t][d] = w * (f[n][d]*c[idx][d])  (np order: value first, then *w) ----
    float* ob = out + (size_t)b * (Nn * TK * Dn);
    constexpr int TOT4 = Nn * TK * Dn / 4;   // 5120 float4 per batch
    for (int i = tid; i < TOT4; i += 256) {
        const int n = i / (TK * Dn / 4);            // / 80
        const int r = i - n * (TK * Dn / 4);
        const int t = r >> 3;
        const int d4 = r & 7;
        const float w = topw[n][t];
        const int m = topi[n][t];
        const float4 f4 = reinterpret_cast<const float4*>(&f_lds[n][0])[d4];
        const float4 c4 = reinterpret_cast<const float4*>(&c_lds[m][0])[d4];
        float4 o;
        { const float vx = f4.x * c4.x; o.x = w * vx; }
        { const float vy = f4.y * c4.y; o.y = w * vy; }
        { const float vz = f4.z * c4.z; o.z = w * vz; }
        { const float vw = f4.w * c4.w; o.w = w * vw; }
        reinterpret_cast<float4*>(ob)[i] = o;
    }
}

extern "C" void kernel_launch(void* const* d_in, const int* in_sizes, int n_in,
                              void* d_out, int out_size, void* d_ws, size_t ws_size,
                              hipStream_t stream) {
    const float* fv = (const float*)d_in[0];   // featureVec [256,64,32]
    const float* cv = (const float*)d_in[1];   // contextVec [256,64,32]
    const float* Wq = (const float*)d_in[2];   // [32,32]
    const float* Wk = (const float*)d_in[3];   // [32,32]
    const float* Wv = (const float*)d_in[4];   // [32,64]
    float* out = (float*)d_out;                // [256, 640, 32]

    sparse_lambda_attn_kernel<<<Bn, 256, 0, stream>>>(fv, cv, Wq, Wk, Wv, out);
}

// Round 6
// 28.128 us; speedup vs baseline: 1.6089x; 1.6089x over previous
//
#include <hip/hip_runtime.h>
#include <math.h>

// Problem constants: B=256, N=64, M=64, d=32, TOPK=10
constexpr int Bn = 256;
constexpr int Nn = 64;
constexpr int Mn = 64;
constexpr int Dn = 32;
constexpr int TK = 10;
constexpr int NT = 1024;   // threads per block (16 waves)

// Correctly-rounded fp32 exp via fp64 (matches np within <=0.5 ulp)
__device__ __forceinline__ float exp_np(float x) {
    return (float)exp((double)x);
}

// Monotone fp32 -> uint32 order map (no NaN inputs here; softmax-derived weights are finite)
__device__ __forceinline__ unsigned int f2u(float f) {
    unsigned int b = __float_as_uint(f);
    return (b & 0x80000000u) ? ~b : (b | 0x80000000u);
}
__device__ __forceinline__ float u2f(unsigned int u) {
    return __uint_as_float((u & 0x80000000u) ? (u ^ 0x80000000u) : ~u);
}

__global__ __launch_bounds__(NT) void sparse_lambda_attn_kernel(
    const float* __restrict__ fv,   // [B,N,D]
    const float* __restrict__ cv,   // [B,M,D]
    const float* __restrict__ Wq,   // [D,D]
    const float* __restrict__ Wk,   // [D,D]
    const float* __restrict__ Wv,   // [D,M]
    float* __restrict__ out)        // [B, N*TK, D]
{
    // Replicate numpy fp32 semantics: NO fma contraction anywhere in this kernel.
    #pragma clang fp contract(off)

    __shared__ float f_lds[Nn][Dn];       // 8 KB
    __shared__ float c_lds[Mn][Dn];       // 8 KB
    __shared__ float bufA[Mn][Dn];        // 8 KB: K logits -> K probs -> Q
    __shared__ float buf16[Mn][Mn + 1];   // 16.25 KB: V -> weight (padded)
    __shared__ float lam[Dn][Mn];         // 8 KB
    __shared__ float colmax[Dn];
    __shared__ float colsum[Dn];
    __shared__ float topw[Nn][TK];        // 2.5 KB
    __shared__ int   topi[Nn][TK];        // 2.5 KB

    const int b = blockIdx.x;
    const int tid = threadIdx.x;

    // ---- stage feature/context tiles (coalesced float4; 512 float4 each) ----
    {
        const float4* f4 = reinterpret_cast<const float4*>(fv + (size_t)b * Nn * Dn);
        const float4* c4 = reinterpret_cast<const float4*>(cv + (size_t)b * Mn * Dn);
        float4* fl = reinterpret_cast<float4*>(&f_lds[0][0]);
        float4* cl = reinterpret_cast<float4*>(&c_lds[0][0]);
        if (tid < 512) fl[tid] = f4[tid];
        else           cl[tid - 512] = c4[tid - 512];
    }
    __syncthreads();

    // ---- K logits[m][k] = sum_d c[m,d]*Wk[d,k]  (sequential mul+add, no fma) ----
    for (int i = tid; i < Mn * Dn; i += NT) {
        const int m = i >> 5, k = i & 31;
        float acc = 0.f;
        for (int d = 0; d < Dn; ++d) {
            const float p = c_lds[m][d] * Wk[d * Dn + k];
            acc = acc + p;
        }
        bufA[m][k] = acc;
    }
    // ---- V[m][v] = sum_d c[m,d]*Wv[d,v] ----
    for (int i = tid; i < Mn * Mn; i += NT) {
        const int m = i >> 6, v = i & 63;
        float acc = 0.f;
        for (int d = 0; d < Dn; ++d) {
            const float p = c_lds[m][d] * Wv[d * Mn + v];
            acc = acc + p;
        }
        buf16[m][v] = acc;
    }
    __syncthreads();

    // ---- softmax over m per column k, np semantics, phase-split for parallelism ----
    // (1) per-column max (exact regardless of order; keep r5's sequential form)
    if (tid < Dn) {
        const int k = tid;
        float mx = bufA[0][k];
        for (int m = 1; m < Mn; ++m) mx = fmaxf(mx, bufA[m][k]);
        colmax[k] = mx;
    }
    __syncthreads();
    // (2) elementwise exp, fully parallel (2048 exps over 1024 threads)
    for (int i = tid; i < Mn * Dn; i += NT) {
        const int m = i >> 5, k = i & 31;
        bufA[m][k] = exp_np(bufA[m][k] - colmax[k]);
    }
    __syncthreads();
    // (3) ascending-m sequential sum per column (order matches np.sum)
    if (tid < Dn) {
        const int k = tid;
        float s = 0.f;
        for (int m = 0; m < Mn; ++m) s = s + bufA[m][k];
        colsum[k] = s;
    }
    __syncthreads();
    // (4) elementwise true division, parallel
    for (int i = tid; i < Mn * Dn; i += NT) {
        const int m = i >> 5, k = i & 31;
        bufA[m][k] = bufA[m][k] / colsum[k];
    }
    __syncthreads();

    // ---- lam[k][v] = sum_m K[m][k]*V[m][v]  (sequential ascending m, no fma) ----
    for (int i = tid; i < Dn * Mn; i += NT) {
        const int k = i >> 6, v = i & 63;
        float acc = 0.f;
        for (int m = 0; m < Mn; ++m) {
            const float p = bufA[m][k] * buf16[m][v];
            acc = acc + p;
        }
        lam[k][v] = acc;
    }
    __syncthreads();   // lam done; bufA (K) and buf16 (V) now dead

    // ---- Q[n][k] = sum_d f[n,d]*Wq[d,k]  (reuse bufA) ----
    for (int i = tid; i < Nn * Dn; i += NT) {
        const int n = i >> 5, k = i & 31;
        float acc = 0.f;
        for (int d = 0; d < Dn; ++d) {
            const float p = f_lds[n][d] * Wq[d * Dn + k];
            acc = acc + p;
        }
        bufA[n][k] = acc;
    }
    __syncthreads();

    // ---- weight[n][v] = sum_k Q[n][k]*lam[k][v]  (reuse buf16) ----
    for (int i = tid; i < Nn * Mn; i += NT) {
        const int n = i >> 6, v = i & 63;
        float acc = 0.f;
        for (int k = 0; k < Dn; ++k) {
            const float p = bufA[n][k] * lam[k][v];
            acc = acc + p;
        }
        buf16[n][v] = acc;
    }
    __syncthreads();

    // ---- top-10 per row: one 16-lane group per row (64 rows x 16 lanes = 1024 threads).
    // Selection is comparison-only -> bit-exact equivalent to r5's serial scan
    // (strict >, lowest index wins ties). Softmax identical arithmetic to r5.
    {
        const int lane = tid & 63;       // lane in wave
        const int g    = tid & 15;       // lane in 16-lane group
        const int n    = tid >> 4;       // row 0..63

        // strip: lane g owns elements m = 4g..4g+3
        float su0v; unsigned su0, su1, su2, su3;
        su0 = f2u(buf16[n][(g << 2) + 0]);
        su1 = f2u(buf16[n][(g << 2) + 1]);
        su2 = f2u(buf16[n][(g << 2) + 2]);
        su3 = f2u(buf16[n][(g << 2) + 3]);
        (void)su0v;
        unsigned avail = 0xFu;

        float val0 = 0.f, myval = 0.f;
        int   myidx = 0;

        #pragma unroll
        for (int t = 0; t < TK; ++t) {
            // best of my strip (ascending j, strict > keeps lowest index)
            unsigned bu = 0u; int bm = 64;
            if ((avail & 1u) && su0 > bu) { bu = su0; bm = (g << 2) + 0; }
            if ((avail & 2u) && su1 > bu) { bu = su1; bm = (g << 2) + 1; }
            if ((avail & 4u) && su2 > bu) { bu = su2; bm = (g << 2) + 2; }
            if ((avail & 8u) && su3 > bu) { bu = su3; bm = (g << 2) + 3; }
            // combine across the 16-lane group: max u, tie -> lower m
            #pragma unroll
            for (int off = 1; off <= 8; off <<= 1) {
                const unsigned ou = __shfl_xor(bu, off);
                const int      om = __shfl_xor(bm, off);
                if (ou > bu || (ou == bu && om < bm)) { bu = ou; bm = om; }
            }
            const float bv = u2f(bu);
            if (t == 0) val0 = bv;
            if (g == t) { myval = bv; myidx = bm; }
            if ((bm >> 2) == g) avail &= ~(1u << (bm & 3));   // owning lane retires it
        }

        // softmax over the 10 selected (order = selection order, same as r5):
        // lane g<10 computes its own exp; ordered ascending-t sum via shuffles.
        const float ev_own = (g < TK) ? exp_np(myval - val0) : 0.f;
        float s = 0.f;
        #pragma unroll
        for (int t = 0; t < TK; ++t) {
            const float e = __shfl(ev_own, (lane & 48) + t);
            s = s + e;
        }
        if (g < TK) {
            topw[n][g] = ev_own / s;   // true division, same as r5
            topi[n][g] = myidx;
        }
    }
    __syncthreads();

    // ---- output: out[b][n*TK+t][d] = w * (f[n][d]*c[idx][d]), float4 coalesced ----
    float* ob = out + (size_t)b * (Nn * TK * Dn);
    constexpr int TOT4 = Nn * TK * Dn / 4;   // 5120 float4 per batch
    for (int i = tid; i < TOT4; i += NT) {
        const int n = i / (TK * Dn / 4);            // / 80
        const int r = i - n * (TK * Dn / 4);
        const int t = r >> 3;
        const int d4 = r & 7;
        const float w = topw[n][t];
        const int m = topi[n][t];
        const float4 f4 = reinterpret_cast<const float4*>(&f_lds[n][0])[d4];
        const float4 c4 = reinterpret_cast<const float4*>(&c_lds[m][0])[d4];
        float4 o;
        { const float vx = f4.x * c4.x; o.x = w * vx; }
        { const float vy = f4.y * c4.y; o.y = w * vy; }
        { const float vz = f4.z * c4.z; o.z = w * vz; }
        { const float vw = f4.w * c4.w; o.w = w * vw; }
        reinterpret_cast<float4*>(ob)[i] = o;
    }
}

extern "C" void kernel_launch(void* const* d_in, const int* in_sizes, int n_in,
                              void* d_out, int out_size, void* d_ws, size_t ws_size,
                              hipStream_t stream) {
    const float* fv = (const float*)d_in[0];   // featureVec [256,64,32]
    const float* cv = (const float*)d_in[1];   // contextVec [256,64,32]
    const float* Wq = (const float*)d_in[2];   // [32,32]
    const float* Wk = (const float*)d_in[3];   // [32,32]
    const float* Wv = (const float*)d_in[4];   // [32,64]
    float* out = (float*)d_out;                // [256, 640, 32]

    sparse_lambda_attn_kernel<<<Bn, NT, 0, stream>>>(fv, cv, Wq, Wk, Wv, out);
}

// Round 7
// 24.700 us; speedup vs baseline: 1.8323x; 1.1388x over previous
//
#include <hip/hip_runtime.h>
#include <math.h>

// Problem constants: B=256, N=64, M=64, d=32, TOPK=10
constexpr int Bn = 256;
constexpr int Nn = 64;
constexpr int Mn = 64;
constexpr int Dn = 32;
constexpr int TK = 10;
constexpr int NT = 1024;   // threads per block (16 waves)

// Correctly-rounded fp32 exp via fp64 (matches np within <=0.5 ulp)
__device__ __forceinline__ float exp_np(float x) {
    return (float)exp((double)x);
}

// Monotone fp32 -> uint32 order map (weights are finite; no NaNs)
__device__ __forceinline__ unsigned int f2u(float f) {
    unsigned int b = __float_as_uint(f);
    return (b & 0x80000000u) ? ~b : (b | 0x80000000u);
}
__device__ __forceinline__ float u2f(unsigned int u) {
    return __uint_as_float((u & 0x80000000u) ? (u ^ 0x80000000u) : ~u);
}

__global__ __launch_bounds__(NT) void sparse_lambda_attn_kernel(
    const float* __restrict__ fv,   // [B,N,D]
    const float* __restrict__ cv,   // [B,M,D]
    const float* __restrict__ Wq,   // [D,D]
    const float* __restrict__ Wk,   // [D,D]
    const float* __restrict__ Wv,   // [D,M]
    float* __restrict__ out)        // [B, N*TK, D]
{
    // Replicate numpy fp32 semantics: NO fma contraction anywhere in this kernel.
    #pragma clang fp contract(off)

    __shared__ float f_lds[Nn][Dn];   // 8 KB
    __shared__ float c_lds[Mn][Dn];   // 8 KB
    __shared__ float wq[Dn][Dn];      // 4 KB  (row-major copy of Wq)
    __shared__ float wk[Dn][Dn];      // 4 KB
    __shared__ float wv[Dn][Mn];      // 8 KB
    __shared__ float Kp[Mn][Dn];      // 8 KB: K logits -> K probs
    __shared__ float Qm[Nn][Dn];      // 8 KB: Q
    __shared__ float Vw[Mn][Mn];      // 16 KB: V -> weight (unpadded; row reads are f4)
    __shared__ float lam[Dn][Mn];     // 8 KB
    __shared__ float colmax[Dn];
    __shared__ float colsum[Dn];
    __shared__ float topw[Nn][TK];    // 2.5 KB
    __shared__ int   topi[Nn][TK];    // 2.5 KB

    const int b = blockIdx.x;
    const int tid = threadIdx.x;

    // ---- stage: f, c, Wq, Wk, Wv -> LDS (all coalesced float4, direct layout) ----
    {
        const float4* F4 = reinterpret_cast<const float4*>(fv + (size_t)b * Nn * Dn);
        const float4* C4 = reinterpret_cast<const float4*>(cv + (size_t)b * Mn * Dn);
        const float4* Q4 = reinterpret_cast<const float4*>(Wq);
        const float4* K4 = reinterpret_cast<const float4*>(Wk);
        const float4* V4 = reinterpret_cast<const float4*>(Wv);
        // item 0: 1024 f4 = f (512) + c (512)
        if (tid < 512) reinterpret_cast<float4*>(&f_lds[0][0])[tid] = F4[tid];
        else           reinterpret_cast<float4*>(&c_lds[0][0])[tid - 512] = C4[tid - 512];
        // item 1: 1024 f4 = wq (256) + wk (256) + wv (512)
        if (tid < 256)      reinterpret_cast<float4*>(&wq[0][0])[tid] = Q4[tid];
        else if (tid < 512) reinterpret_cast<float4*>(&wk[0][0])[tid - 256] = K4[tid - 256];
        else                reinterpret_cast<float4*>(&wv[0][0])[tid - 512] = V4[tid - 512];
    }
    __syncthreads();

    // ---- Phase A (one barrier): K (threads 0-511), Q (threads 512-1023), V (all threads).
    // Each output = sequential ascending-d mul-then-add, identical to r6 bit-for-bit.
    {
        if (tid < 512) {
            // K logits: thread = (m, k4): Kp[m][k4*4 .. +3]
            const int m = tid >> 3, k4 = (tid & 7) << 2;
            float a0 = 0.f, a1 = 0.f, a2 = 0.f, a3 = 0.f;
            for (int d = 0; d < Dn; ++d) {
                const float cc = c_lds[m][d];
                const float4 w = *reinterpret_cast<const float4*>(&wk[d][k4]);
                a0 = a0 + cc * w.x;
                a1 = a1 + cc * w.y;
                a2 = a2 + cc * w.z;
                a3 = a3 + cc * w.w;
            }
            float4 r; r.x = a0; r.y = a1; r.z = a2; r.w = a3;
            *reinterpret_cast<float4*>(&Kp[m][k4]) = r;
        } else {
            // Q: thread = (n, k4): Qm[n][k4*4 .. +3]
            const int t = tid - 512;
            const int n = t >> 3, k4 = (t & 7) << 2;
            float a0 = 0.f, a1 = 0.f, a2 = 0.f, a3 = 0.f;
            for (int d = 0; d < Dn; ++d) {
                const float ff = f_lds[n][d];
                const float4 w = *reinterpret_cast<const float4*>(&wq[d][k4]);
                a0 = a0 + ff * w.x;
                a1 = a1 + ff * w.y;
                a2 = a2 + ff * w.z;
                a3 = a3 + ff * w.w;
            }
            float4 r; r.x = a0; r.y = a1; r.z = a2; r.w = a3;
            *reinterpret_cast<float4*>(&Qm[n][k4]) = r;
        }
        // V: thread = (m, v4): Vw[m][v4*4 .. +3]
        {
            const int m = tid >> 4, v4 = (tid & 15) << 2;
            float a0 = 0.f, a1 = 0.f, a2 = 0.f, a3 = 0.f;
            for (int d = 0; d < Dn; ++d) {
                const float cc = c_lds[m][d];
                const float4 w = *reinterpret_cast<const float4*>(&wv[d][v4]);
                a0 = a0 + cc * w.x;
                a1 = a1 + cc * w.y;
                a2 = a2 + cc * w.z;
                a3 = a3 + cc * w.w;
            }
            float4 r; r.x = a0; r.y = a1; r.z = a2; r.w = a3;
            *reinterpret_cast<float4*>(&Vw[m][v4]) = r;
        }
    }
    __syncthreads();

    // ---- softmax over m per column k (np semantics, phase-split) ----
    if (tid < Dn) {    // (1) per-column max (order-exact for max regardless)
        const int k = tid;
        float mx = Kp[0][k];
        for (int m = 1; m < Mn; ++m) mx = fmaxf(mx, Kp[m][k]);
        colmax[k] = mx;
    }
    __syncthreads();
    for (int i = tid; i < Mn * Dn; i += NT) {   // (2) parallel exp
        const int m = i >> 5, k = i & 31;
        Kp[m][k] = exp_np(Kp[m][k] - colmax[k]);
    }
    __syncthreads();
    if (tid < Dn) {    // (3) ascending-m sequential sum (np order)
        const int k = tid;
        float s = 0.f;
        for (int m = 0; m < Mn; ++m) s = s + Kp[m][k];
        colsum[k] = s;
    }
    __syncthreads();
    for (int i = tid; i < Mn * Dn; i += NT) {   // (4) parallel true division
        const int m = i >> 5, k = i & 31;
        Kp[m][k] = Kp[m][k] / colsum[k];
    }
    __syncthreads();

    // ---- lam[k][v] = sum_m K[m][k]*V[m][v]: thread = (k, v4), 512 threads ----
    if (tid < 512) {
        const int k = tid >> 4, v4 = (tid & 15) << 2;
        float a0 = 0.f, a1 = 0.f, a2 = 0.f, a3 = 0.f;
        for (int m = 0; m < Mn; ++m) {
            const float kk = Kp[m][k];
            const float4 vv = *reinterpret_cast<const float4*>(&Vw[m][v4]);
            a0 = a0 + kk * vv.x;
            a1 = a1 + kk * vv.y;
            a2 = a2 + kk * vv.z;
            a3 = a3 + kk * vv.w;
        }
        float4 r; r.x = a0; r.y = a1; r.z = a2; r.w = a3;
        *reinterpret_cast<float4*>(&lam[k][v4]) = r;
    }
    __syncthreads();

    // ---- weight[n][v] = sum_k Q[n][k]*lam[k][v]: thread = (n, v4), 1024 threads; overwrite Vw ----
    {
        const int n = tid >> 4, v4 = (tid & 15) << 2;
        float a0 = 0.f, a1 = 0.f, a2 = 0.f, a3 = 0.f;
        for (int k = 0; k < Dn; ++k) {
            const float qq = Qm[n][k];
            const float4 ll = *reinterpret_cast<const float4*>(&lam[k][v4]);
            a0 = a0 + qq * ll.x;
            a1 = a1 + qq * ll.y;
            a2 = a2 + qq * ll.z;
            a3 = a3 + qq * ll.w;
        }
        __syncthreads();   // ensure all lam reads complete before overwriting Vw? (Vw dead, lam distinct) -- actually Vw writes race with nothing; barrier kept for clarity of Vw reuse
        float4 r; r.x = a0; r.y = a1; r.z = a2; r.w = a3;
        *reinterpret_cast<float4*>(&Vw[n][v4]) = r;
    }
    __syncthreads();

    // ---- top-10 per row: 16-lane group per row; comparison-only, bit-exact vs r6 ----
    {
        const int lane = tid & 63;
        const int g    = tid & 15;
        const int n    = tid >> 4;

        const float4 s4 = *reinterpret_cast<const float4*>(&Vw[n][g << 2]);
        unsigned su0 = f2u(s4.x), su1 = f2u(s4.y), su2 = f2u(s4.z), su3 = f2u(s4.w);
        unsigned avail = 0xFu;

        float val0 = 0.f, myval = 0.f;
        int   myidx = 0;

        #pragma unroll
        for (int t = 0; t < TK; ++t) {
            unsigned bu = 0u; int bm = 64;
            if ((avail & 1u) && su0 > bu) { bu = su0; bm = (g << 2) + 0; }
            if ((avail & 2u) && su1 > bu) { bu = su1; bm = (g << 2) + 1; }
            if ((avail & 4u) && su2 > bu) { bu = su2; bm = (g << 2) + 2; }
            if ((avail & 8u) && su3 > bu) { bu = su3; bm = (g << 2) + 3; }
            #pragma unroll
            for (int off = 1; off <= 8; off <<= 1) {
                const unsigned ou = __shfl_xor(bu, off);
                const int      om = __shfl_xor(bm, off);
                if (ou > bu || (ou == bu && om < bm)) { bu = ou; bm = om; }
            }
            const float bv = u2f(bu);
            if (t == 0) val0 = bv;
            if (g == t) { myval = bv; myidx = bm; }
            if ((bm >> 2) == g) avail &= ~(1u << (bm & 3));
        }

        const float ev_own = (g < TK) ? exp_np(myval - val0) : 0.f;
        float s = 0.f;
        #pragma unroll
        for (int t = 0; t < TK; ++t) {
            const float e = __shfl(ev_own, (lane & 48) + t);
            s = s + e;
        }
        if (g < TK) {
            topw[n][g] = ev_own / s;
            topi[n][g] = myidx;
        }
    }
    __syncthreads();

    // ---- output: out[b][n*TK+t][d] = w * (f[n][d]*c[idx][d]), float4 coalesced ----
    float* ob = out + (size_t)b * (Nn * TK * Dn);
    constexpr int TOT4 = Nn * TK * Dn / 4;   // 5120 float4 per batch
    for (int i = tid; i < TOT4; i += NT) {
        const int n = i / (TK * Dn / 4);            // / 80
        const int r = i - n * (TK * Dn / 4);
        const int t = r >> 3;
        const int d4 = r & 7;
        const float w = topw[n][t];
        const int m = topi[n][t];
        const float4 f4 = reinterpret_cast<const float4*>(&f_lds[n][0])[d4];
        const float4 c4 = reinterpret_cast<const float4*>(&c_lds[m][0])[d4];
        float4 o;
        { const float vx = f4.x * c4.x; o.x = w * vx; }
        { const float vy = f4.y * c4.y; o.y = w * vy; }
        { const float vz = f4.z * c4.z; o.z = w * vz; }
        { const float vw = f4.w * c4.w; o.w = w * vw; }
        reinterpret_cast<float4*>(ob)[i] = o;
    }
}

extern "C" void kernel_launch(void* const* d_in, const int* in_sizes, int n_in,
                              void* d_out, int out_size, void* d_ws, size_t ws_size,
                              hipStream_t stream) {
    const float* fv = (const float*)d_in[0];   // featureVec [256,64,32]
    const float* cv = (const float*)d_in[1];   // contextVec [256,64,32]
    const float* Wq = (const float*)d_in[2];   // [32,32]
    const float* Wk = (const float*)d_in[3];   // [32,32]
    const float* Wv = (const float*)d_in[4];   // [32,64]
    float* out = (float*)d_out;                // [256, 640, 32]

    sparse_lambda_attn_kernel<<<Bn, NT, 0, stream>>>(fv, cv, Wq, Wk, Wv, out);
}